// Round 3
// baseline (7672.749 us; speedup 1.0000x reference)
//
#include <hip/hip_runtime.h>
#include <math.h>

// ---------------------------------------------------------------------------
// LphaLoss: blockwise VGG19(conv3_1) FFT-phase cosine mask + masked L1.
// fp32 everywhere (mask threshold sim>=0.2 is a discontinuity; bf16 risky).
//
// ws layout (floats), chunked over T tasks (T adaptive to ws_size):
//   pool1 : [T][64][16][16]      = T*16384
//   pool2 : [2][T][128][8][8]    = T*16384
//   mask  : [1024]
//   accum : [1]
// footprint = (T*32768 + 2048) * 4 bytes.  T in {1024,...,8}.
// ---------------------------------------------------------------------------

__device__ __forceinline__ float wave_reduce_sum(float v) {
#pragma unroll
  for (int off = 32; off > 0; off >>= 1) v += __shfl_down(v, off);
  return v;
}

__global__ void k0_zero(float* acc) { acc[0] = 0.f; }

// ---------------- K1: conv1_1+relu -> conv1_2+relu -> pool1 ----------------
// one workgroup (512 thr) per 32x32 block-task. blockIdx.x local to chunk.
__global__ __launch_bounds__(512) void k1_conv1(const float* __restrict__ src,
                                                const float* __restrict__ w1,
                                                const float* __restrict__ b1,
                                                const float* __restrict__ w2,
                                                const float* __restrict__ b2,
                                                float* __restrict__ pool1,
                                                int task_base) {
  const int btl = blockIdx.x;                // local task (pool1 index)
  const int bt = btl + task_base;            // global task (src index)
  const int img = bt >> 6, by = (bt >> 3) & 7, bx = bt & 7;
  const int tid = threadIdx.x;

  __shared__ float lin[3 * 34 * 34];         // normalized, zero-padded input
  __shared__ float w1s[64 * 27];
  __shared__ float b1s[64], b2s[64];
  __shared__ float c11[64 * 10 * 34];        // conv1_1 rows (quarter + halo), col-padded

  for (int idx = tid; idx < 3 * 34 * 34; idx += 512) {
    int c = idx / 1156;
    int rm = idx - c * 1156;
    int row = rm / 34;
    int xx = rm - row * 34 - 1;
    int yy = row - 1;
    float v = 0.f;
    if (yy >= 0 && yy < 32 && xx >= 0 && xx < 32) {
      float m = (c == 0) ? 0.485f : (c == 1) ? 0.456f : 0.406f;
      float sd = (c == 0) ? 0.229f : (c == 1) ? 0.224f : 0.225f;
      v = (src[((img * 3 + c) * 256 + (by * 32 + yy)) * 256 + (bx * 32 + xx)] - m) / sd;
    }
    lin[idx] = v;
  }
  for (int idx = tid; idx < 64 * 27; idx += 512) w1s[idx] = w1[idx];
  if (tid < 64) b1s[tid] = b1[tid];
  else if (tid < 128) b2s[tid - 64] = b2[tid - 64];

  const int cogs = __builtin_amdgcn_readfirstlane(tid >> 6);  // wave id = co-group
  const int lane = tid & 63;
  const int pr = lane >> 4;     // pool row within quarter (0..3)
  const int pcx = lane & 15;    // pool col (0..15)

  __syncthreads();

  for (int q = 0; q < 4; ++q) {
    const int y0 = q * 8;
    if (q) __syncthreads();
    // conv1_1 + relu into c11 (rows y0-1 .. y0+8, cols padded by 1)
    for (int e = tid; e < 64 * 10 * 34; e += 512) {
      int ch = e / 340;
      int rm = e - ch * 340;
      int r = rm / 34;
      int xp = rm - r * 34;
      int y = y0 - 1 + r;
      int x = xp - 1;
      float v = 0.f;
      if (y >= 0 && y < 32 && x >= 0 && x < 32) {
        float a = b1s[ch];
        const float* wp = &w1s[ch * 27];
#pragma unroll
        for (int ci = 0; ci < 3; ++ci) {
          const float* lp = &lin[ci * 1156 + y * 34 + x];
#pragma unroll
          for (int ky = 0; ky < 3; ++ky)
#pragma unroll
            for (int kx = 0; kx < 3; ++kx)
              a = fmaf(lp[ky * 34 + kx], wp[ci * 9 + ky * 3 + kx], a);
        }
        v = fmaxf(a, 0.f);
      }
      c11[e] = v;
    }
    __syncthreads();

    // conv1_2 (+bias+relu) + 2x2 pool. 8 co per wave, 2x2 window per lane.
    float acc[8][4];
#pragma unroll
    for (int a = 0; a < 8; ++a)
#pragma unroll
      for (int p = 0; p < 4; ++p) acc[a][p] = 0.f;

    const float* w2g = w2 + cogs * 8 * 576;    // wave-uniform -> scalar-load path
    for (int ci = 0; ci < 64; ++ci) {
      const float* c1b = &c11[ci * 340];
      const float* w2c = w2g + ci * 9;
#pragma unroll
      for (int ky = 0; ky < 3; ++ky) {
#pragma unroll
        for (int kx = 0; kx < 3; ++kx) {
          float wv[8];
#pragma unroll
          for (int a = 0; a < 8; ++a) wv[a] = w2c[a * 576 + ky * 3 + kx];
#pragma unroll
          for (int d = 0; d < 2; ++d) {
            const float* rp_ = &c1b[(2 * pr + d + ky) * 34 + 2 * pcx + kx];
#pragma unroll
            for (int xx = 0; xx < 2; ++xx) {
              float inv = rp_[xx];
#pragma unroll
              for (int a = 0; a < 8; ++a)
                acc[a][d * 2 + xx] = fmaf(inv, wv[a], acc[a][d * 2 + xx]);
            }
          }
        }
      }
    }
    const int prow = q * 4 + pr;
#pragma unroll
    for (int a = 0; a < 8; ++a) {
      const int co = cogs * 8 + a;
      const float bb = b2s[co];
      float m0 = fmaxf(fmaxf(acc[a][0] + bb, 0.f), fmaxf(acc[a][1] + bb, 0.f));
      float m1 = fmaxf(fmaxf(acc[a][2] + bb, 0.f), fmaxf(acc[a][3] + bb, 0.f));
      pool1[((btl * 64 + co) * 16 + prow) * 16 + pcx] = fmaxf(m0, m1);
    }
  }
}

// ---------------- K2: conv2_1+relu -> conv2_2+relu -> pool2 ----------------
// all indices local to chunk.
__global__ __launch_bounds__(512) void k2_conv2(const float* __restrict__ pool1,
                                                const float* __restrict__ w3,
                                                const float* __restrict__ b3,
                                                const float* __restrict__ w4,
                                                const float* __restrict__ b4,
                                                float* __restrict__ pool2) {
  const int bt = blockIdx.x;
  const int tid = threadIdx.x;
  __shared__ float lin2[64 * 256];           // pool1 task slice (16x16, unpadded)
  __shared__ float c21[128 * 10 * 18];       // conv2_1 half-tile + halo, col-padded
  __shared__ float b3s[128], b4s[128];

  for (int idx = tid; idx < 64 * 256; idx += 512) lin2[idx] = pool1[bt * 16384 + idx];
  if (tid < 128) b3s[tid] = b3[tid];
  else if (tid < 256) b4s[tid - 128] = b4[tid - 128];

  const int wv_id = __builtin_amdgcn_readfirstlane(tid >> 6);  // 0..7
  const int lane = tid & 63;

  __syncthreads();

  for (int h = 0; h < 2; ++h) {
    const int y0 = h * 8;
    if (h) __syncthreads();
    // ---- conv2_1 (+bias+relu) into c21 rows y0-1..y0+8 ----
    {
      const int rq = lane >> 4;   // 0..3
      const int xc = lane & 15;
#pragma unroll
      for (int p = 0; p < 2; ++p) {
        const int cg = wv_id * 2 + p;                 // 0..15
        const float* w3g = w3 + cg * 8 * 576;
        float a21[8][3];
#pragma unroll
        for (int a = 0; a < 8; ++a)
#pragma unroll
          for (int rr = 0; rr < 3; ++rr) a21[a][rr] = 0.f;
        for (int ci = 0; ci < 64; ++ci) {
          const float* l2 = &lin2[ci * 256];
          const float* w3c = w3g + ci * 9;
#pragma unroll
          for (int ky = 0; ky < 3; ++ky) {
#pragma unroll
            for (int kx = 0; kx < 3; ++kx) {
              float wv[8];
#pragma unroll
              for (int a = 0; a < 8; ++a) wv[a] = w3c[a * 576 + ky * 3 + kx];
              const int xin = xc + kx - 1;
              const bool xok = (xin >= 0) && (xin < 16);
#pragma unroll
              for (int rr = 0; rr < 3; ++rr) {
                const int r = rq + rr * 4;            // 0..11 (valid <10)
                const int yin = y0 - 2 + r + ky;
                float inv = 0.f;
                if (xok && r < 10 && yin >= 0 && yin < 16) inv = l2[yin * 16 + xin];
#pragma unroll
                for (int a = 0; a < 8; ++a) a21[a][rr] = fmaf(inv, wv[a], a21[a][rr]);
              }
            }
          }
        }
#pragma unroll
        for (int a = 0; a < 8; ++a) {
          const int ch = cg * 8 + a;
          const float bb = b3s[ch];
#pragma unroll
          for (int rr = 0; rr < 3; ++rr) {
            const int r = rq + rr * 4;
            if (r < 10) {
              const int y = y0 - 1 + r;
              float v = (y >= 0 && y < 16) ? fmaxf(a21[a][rr] + bb, 0.f) : 0.f;
              c21[(ch * 10 + r) * 18 + xc + 1] = v;
              if (xc == 0) c21[(ch * 10 + r) * 18 + 0] = 0.f;
              if (xc == 15) c21[(ch * 10 + r) * 18 + 17] = 0.f;
            }
          }
        }
      }
    }
    __syncthreads();
    // ---- conv2_2 (+bias+relu) + 2x2 pool ----
    {
      const int w = lane >> 1;     // window id 0..31
      const int d = lane & 1;      // row within window
      const int wr = w >> 3;       // pool row (within half)
      const int wc = w & 7;        // pool col
      const int rl = 2 * wr + d;   // conv row local 0..7
#pragma unroll
      for (int p = 0; p < 2; ++p) {
        const int cg = wv_id * 2 + p;
        const float* w4g = w4 + cg * 8 * 1152;
        float a22[8][2];
#pragma unroll
        for (int a = 0; a < 8; ++a) { a22[a][0] = 0.f; a22[a][1] = 0.f; }
        for (int ci = 0; ci < 128; ++ci) {
          const float* c2b = &c21[ci * 180];
          const float* w4c = w4g + ci * 9;
#pragma unroll
          for (int ky = 0; ky < 3; ++ky) {
            const float* rp_ = &c2b[(rl + ky) * 18 + 2 * wc];
#pragma unroll
            for (int kx = 0; kx < 3; ++kx) {
              float wv[8];
#pragma unroll
              for (int a = 0; a < 8; ++a) wv[a] = w4c[a * 1152 + ky * 3 + kx];
#pragma unroll
              for (int xx = 0; xx < 2; ++xx) {
                float inv = rp_[xx + kx];
#pragma unroll
                for (int a = 0; a < 8; ++a) a22[a][xx] = fmaf(inv, wv[a], a22[a][xx]);
              }
            }
          }
        }
#pragma unroll
        for (int a = 0; a < 8; ++a) {
          const int ch = cg * 8 + a;
          const float bb = b4s[ch];
          float m = fmaxf(fmaxf(a22[a][0] + bb, 0.f), fmaxf(a22[a][1] + bb, 0.f));
          float o = __shfl_xor(m, 1);
          m = fmaxf(m, o);
          if (d == 0) pool2[(bt * 128 + ch) * 64 + (h * 4 + wr) * 8 + wc] = m;
        }
      }
    }
  }
}

// -------- K3: conv3_1 (both streams) + FFT2 phase + cosine sim -> mask -----
__global__ __launch_bounds__(256) void k3_conv3_fft(const float* __restrict__ pool2,
                                                    const float* __restrict__ w5,
                                                    const float* __restrict__ b5,
                                                    float* __restrict__ maskp,
                                                    int task_base, int T) {
  const int b = blockIdx.x;                  // local task
  const int tid = threadIdx.x;               // = output channel co
  __shared__ float lin[128 * 64];
  __shared__ float p1s[256 * 64];            // phases of stream 0
  __shared__ float rbuf[12];

  const float bias = b5[tid];
  float n1 = 0.f, n2 = 0.f, dt = 0.f;

  for (int s = 0; s < 2; ++s) {
    __syncthreads();
    for (int idx = tid; idx < 8192; idx += 256)
      lin[idx] = pool2[(size_t)(s * T + b) * 8192 + idx];
    __syncthreads();

    float acc[64];
#pragma unroll
    for (int p = 0; p < 64; ++p) acc[p] = bias;

    const float* w5g = w5 + tid * 1152;
    for (int ci = 0; ci < 128; ++ci) {
      float wv[9];
#pragma unroll
      for (int k = 0; k < 9; ++k) wv[k] = w5g[ci * 9 + k];
      const float* lr = &lin[ci * 64];
#pragma unroll
      for (int ir = 0; ir < 8; ++ir) {
        float row[10];
        row[0] = 0.f; row[9] = 0.f;
#pragma unroll
        for (int x = 0; x < 8; ++x) row[x + 1] = lr[ir * 8 + x];
#pragma unroll
        for (int ky = 0; ky < 3; ++ky) {
          const int y = ir + 1 - ky;        // compile-time after unroll
          if (y >= 0 && y < 8) {
#pragma unroll
            for (int kx = 0; kx < 3; ++kx) {
              const float wgt = wv[ky * 3 + kx];
#pragma unroll
              for (int x = 0; x < 8; ++x)
                acc[y * 8 + x] = fmaf(row[x + kx], wgt, acc[y * 8 + x]);
            }
          }
        }
      }
    }
    // ---- 8x8 DFT2 (twiddles fold to {0,+-1,+-sqrt2/2}) ----
    const float C8[8] = {1.f, 0.70710678118654752f, 0.f, -0.70710678118654752f,
                         -1.f, -0.70710678118654752f, 0.f, 0.70710678118654752f};
    const float S8[8] = {0.f, 0.70710678118654752f, 1.f, 0.70710678118654752f,
                         0.f, -0.70710678118654752f, -1.f, -0.70710678118654752f};
    float im[64];
#pragma unroll
    for (int y = 0; y < 8; ++y) {           // row DFTs (real input)
      float re[8], imv[8];
#pragma unroll
      for (int k = 0; k < 8; ++k) {
        float sr = 0.f, si = 0.f;
#pragma unroll
        for (int x = 0; x < 8; ++x) {
          const int m = (k * x) & 7;
          sr = fmaf(acc[y * 8 + x], C8[m], sr);
          si = fmaf(acc[y * 8 + x], -S8[m], si);
        }
        re[k] = sr; imv[k] = si;
      }
#pragma unroll
      for (int k = 0; k < 8; ++k) { acc[y * 8 + k] = re[k]; im[y * 8 + k] = imv[k]; }
    }
#pragma unroll
    for (int k = 0; k < 8; ++k) {           // col DFTs + phase + accumulate
#pragma unroll
      for (int k2 = 0; k2 < 8; ++k2) {
        float sr = 0.f, si = 0.f;
#pragma unroll
        for (int yy = 0; yy < 8; ++yy) {
          const int m = (k2 * yy) & 7;
          const float wr = C8[m], wi = -S8[m];
          const float ar = acc[yy * 8 + k], ai = im[yy * 8 + k];
          sr += ar * wr - ai * wi;
          si += ar * wi + ai * wr;
        }
        const float ph = atan2f(si, sr);
        const int pidx = k2 * 8 + k;
        if (s == 0) {
          p1s[tid * 64 + pidx] = ph;
          n1 = fmaf(ph, ph, n1);
        } else {
          const float q = p1s[tid * 64 + pidx];
          dt = fmaf(ph, q, dt);
          n2 = fmaf(ph, ph, n2);
        }
      }
    }
  }
  dt = wave_reduce_sum(dt);
  n1 = wave_reduce_sum(n1);
  n2 = wave_reduce_sum(n2);
  if ((tid & 63) == 0) {
    rbuf[(tid >> 6) * 3 + 0] = dt;
    rbuf[(tid >> 6) * 3 + 1] = n1;
    rbuf[(tid >> 6) * 3 + 2] = n2;
  }
  __syncthreads();
  if (tid == 0) {
    float D = 0.f, A = 0.f, B2 = 0.f;
#pragma unroll
    for (int w = 0; w < 4; ++w) { D += rbuf[w * 3]; A += rbuf[w * 3 + 1]; B2 += rbuf[w * 3 + 2]; }
    const float den = fmaxf(sqrtf(A) * sqrtf(B2), 1e-8f);
    const float sim = D / den;
    maskp[task_base + b] = (sim >= 0.2f) ? 1.f : 0.f;
  }
}

// ---------------- K4: masked L1 partial reduce ----------------
__global__ __launch_bounds__(256) void k4_l1(const float4* __restrict__ pred2,
                                             const float4* __restrict__ target,
                                             const float* __restrict__ maskp,
                                             float* __restrict__ accum) {
  const int gid = blockIdx.x * 256 + threadIdx.x;
  float part = 0.f;
  for (int e = gid; e < 786432; e += 262144) {   // 16*3*256*256/4
    const int flat = e << 2;
    const int i = flat / 196608;
    const int rem = flat - i * 196608;
    const int pix = rem & 65535;
    const int y = pix >> 8, x = pix & 255;
    const int b = (i << 6) + ((y >> 5) << 3) + (x >> 5);
    if (maskp[b] != 0.f) {
      const float4 p = pred2[e];
      const float4 t = target[e];
      part += fabsf(p.x - t.x) + fabsf(p.y - t.y) + fabsf(p.z - t.z) + fabsf(p.w - t.w);
    }
  }
  part = wave_reduce_sum(part);
  __shared__ float rb[4];
  if ((threadIdx.x & 63) == 0) rb[threadIdx.x >> 6] = part;
  __syncthreads();
  if (threadIdx.x == 0) atomicAdd(accum, rb[0] + rb[1] + rb[2] + rb[3]);
}

// ---------------- K5: finalize ----------------
__global__ __launch_bounds__(256) void k5_final(const float* __restrict__ accum,
                                                const float* __restrict__ maskp,
                                                float* __restrict__ out) {
  float c = 0.f;
  for (int i = threadIdx.x; i < 1024; i += 256) c += maskp[i];
  c = wave_reduce_sum(c);
  __shared__ float rb[4];
  if ((threadIdx.x & 63) == 0) rb[threadIdx.x >> 6] = c;
  __syncthreads();
  if (threadIdx.x == 0) {
    const float cnt = rb[0] + rb[1] + rb[2] + rb[3];
    out[0] = accum[0] / (cnt * 1024.f + 1e-6f);
  }
}

// ---------------------------------------------------------------------------
extern "C" void kernel_launch(void* const* d_in, const int* in_sizes, int n_in,
                              void* d_out, int out_size, void* d_ws, size_t ws_size,
                              hipStream_t stream) {
  (void)in_sizes; (void)n_in; (void)out_size;
  const float* pred1  = (const float*)d_in[0];
  const float* pred2  = (const float*)d_in[1];
  const float* target = (const float*)d_in[2];
  const float* w1 = (const float*)d_in[3];  const float* b1 = (const float*)d_in[4];
  const float* w2 = (const float*)d_in[5];  const float* b2 = (const float*)d_in[6];
  const float* w3 = (const float*)d_in[7];  const float* b3 = (const float*)d_in[8];
  const float* w4 = (const float*)d_in[9];  const float* b4 = (const float*)d_in[10];
  const float* w5 = (const float*)d_in[11]; const float* b5 = (const float*)d_in[12];

  // Pick the largest chunk size T whose ws footprint fits.
  // footprint(T) = (T*32768 + 2048) floats.
  int T = 8;
  for (int cand = 1024; cand >= 8; cand >>= 1) {
    const size_t need = ((size_t)cand * 32768 + 2048) * sizeof(float);
    if (need <= ws_size) { T = cand; break; }
  }

  float* ws    = (float*)d_ws;
  float* pool1 = ws;                              // T*16384 floats
  float* pool2 = ws + (size_t)T * 16384;          // 2*T*8192 floats
  float* maskp = ws + (size_t)T * 32768;          // 1024
  float* accum = maskp + 1024;                    // 1

  float* outp = (float*)d_out;

  k0_zero<<<1, 1, 0, stream>>>(accum);
  const int nchunks = 1024 / T;
  for (int c = 0; c < nchunks; ++c) {
    const int base = c * T;
    for (int s = 0; s < 2; ++s) {
      const float* src = s ? target : pred1;
      k1_conv1<<<T, 512, 0, stream>>>(src, w1, b1, w2, b2, pool1, base);
      k2_conv2<<<T, 512, 0, stream>>>(pool1, w3, b3, w4, b4,
                                      pool2 + (size_t)s * T * 8192);
    }
    k3_conv3_fft<<<T, 256, 0, stream>>>(pool2, w5, b5, maskp, base, T);
  }
  k4_l1<<<1024, 256, 0, stream>>>((const float4*)pred2, (const float4*)target, maskp, accum);
  k5_final<<<1, 256, 0, stream>>>(accum, maskp, outp);
}